// Round 4
// baseline (97.401 us; speedup 1.0000x reference)
//
#include <hip/hip_runtime.h>

#define NU_C 0.3f
#define EQ_W 0.1f
#define EN_W 0.1f

// Structured-grid formulation (R2): R is a constant-coefficient stencil
// gather, energy is per-cell, no atomics into R (R3: per-block partials,
// no same-address atomics). R4: interior nodes (99.6%) use the analytically
// collapsed 8-point stencil:
//   fx = (fC/2)[ (4+4hs)c.x - 2(n.x+s.x) - 2hs(e.x+w.x)
//                + (nu+hs)(2c.y - e.y-s.y-n.y-w.y + sw.y + ne.y) ]
//   fy = (fC/2)[ (4+4hs)c.y - 2(e.y+w.y) - 2hs(n.y+s.y)
//                + (nu+hs)(2c.x - e.x-s.x-n.x-w.x + sw.x + ne.x) ]
// (hs = (1-nu)/2; coefficient sums are 0 = translation invariance check).
// Border nodes keep the general 6-triangle path.

__global__ __launch_bounds__(256)
void pino_stencil_kernel(const float2* __restrict__ up,
                         const float2* __restrict__ ut,
                         float2* __restrict__ partials,
                         int g, float k, float q, float area) {
    const float fC = 1.f / (1.f - NU_C * NU_C);   // plane-stress factor
    const float hs = (1.f - NU_C) * 0.5f;          // C[2][2] / fC
    const float hf = 0.5f * fC;
    const float w_c  = 4.f + 4.f * hs;             // 5.4
    const float w_di = 2.f * hs;                   // 0.7
    const float w_x  = NU_C + hs;                  // 0.65

    const int j = blockIdx.x * 64 + (threadIdx.x & 63);
    const int i = blockIdx.y * 4 + (threadIdx.x >> 6);

    float r2 = 0.f, energy = 0.f;

    if (i > 0 && i < g - 1 && j > 0 && j < g - 1) {
        // ---------- interior fast path ----------
        const int idx = i * g + j;
        const float2 Uc  = up[idx];
        const float2 Ue  = up[idx + 1];
        const float2 Uw  = up[idx - 1];
        const float2 Un  = up[idx - g];
        const float2 Us  = up[idx + g];
        const float2 Usw = up[idx + g - 1];
        const float2 Une = up[idx - g + 1];
        const float2 Use = up[idx + g + 1];

        const float Sy = 2.f * Uc.y - Ue.y - Us.y - Un.y - Uw.y + Usw.y + Une.y;
        const float Sx = 2.f * Uc.x - Ue.x - Us.x - Un.x - Uw.x + Usw.x + Une.x;
        const float fx = hf * (w_c * Uc.x - 2.f * (Us.x + Un.x)
                               - w_di * (Ue.x + Uw.x) + w_x * Sy);
        const float fy = hf * (w_c * Uc.y - 2.f * (Ue.y + Uw.y)
                               - w_di * (Us.y + Un.y) + w_x * Sx);
        r2 = fx * fx + fy * fy;

        // energy for cell (i,j): tri1 + tri2 on u_err, raw-difference form
        const float2 Tc  = ut[idx];
        const float2 Te  = ut[idx + 1];
        const float2 Ts  = ut[idx + g];
        const float2 Tse = ut[idx + g + 1];
        const float dcx = Uc.x - Tc.x,   dcy = Uc.y - Tc.y;
        const float dex = Ue.x - Te.x,   dey = Ue.y - Te.y;
        const float dsx = Us.x - Ts.x,   dsy = Us.y - Ts.y;
        const float dqx = Use.x - Tse.x, dqy = Use.y - Tse.y;
        float a0 = dsx - dcx;
        float a1 = dey - dcy;
        float a2 = (dex - dcx) + (dsy - dcy);
        energy  = hf * (a0 * a0 + 2.f * NU_C * a0 * a1 + a1 * a1 + hs * a2 * a2);
        a0 = dqx - dex;
        a1 = dqy - dsy;
        a2 = (dqx - dsx) + (dqy - dey);
        energy += hf * (a0 * a0 + 2.f * NU_C * a0 * a1 + a1 * a1 + hs * a2 * a2);
    } else if (i < g && j < g) {
        // ---------- border general path (unchanged from R3) ----------
        const int im = (i > 0) ? i - 1 : 0;
        const int ip = (i < g - 1) ? i + 1 : g - 1;
        const int jm = (j > 0) ? j - 1 : 0;
        const int jp = (j < g - 1) ? j + 1 : g - 1;
        const bool iok = (i < g - 1), jok = (j < g - 1);
        const bool i0 = (i > 0), j0 = (j > 0);

        const float2 Uc  = up[(size_t)i  * g + j ];
        const float2 Ue  = up[(size_t)i  * g + jp];
        const float2 Uw  = up[(size_t)i  * g + jm];
        const float2 Un  = up[(size_t)im * g + j ];
        const float2 Us  = up[(size_t)ip * g + j ];
        const float2 Usw = up[(size_t)ip * g + jm];
        const float2 Une = up[(size_t)im * g + jp];

        float fx = 0.f, fy = 0.f;
        float e0, e1, e2, s0, s1, s2;

        if (iok && jok) {   // T1: tri1(i,j), center = node a
            e0 = k * (Us.x - Uc.x);
            e1 = k * (Ue.y - Uc.y);
            e2 = k * ((Ue.x - Uc.x) + (Us.y - Uc.y));
            s0 = fC * (e0 + NU_C * e1); s1 = fC * (NU_C * e0 + e1); s2 = fC * hs * e2;
            fx -= q * (s0 + s2); fy -= q * (s1 + s2);
        }
        if (iok && j0) {    // T2: tri1(i,j-1), center = node b
            e0 = k * (Usw.x - Uw.x);
            e1 = k * (Uc.y - Uw.y);
            e2 = k * ((Uc.x - Uw.x) + (Usw.y - Uw.y));
            s0 = fC * (e0 + NU_C * e1); s1 = fC * (NU_C * e0 + e1); s2 = fC * hs * e2;
            fx += q * s2; fy += q * s1;
        }
        if (i0 && jok) {    // T3: tri1(i-1,j), center = node c
            e0 = k * (Uc.x - Un.x);
            e1 = k * (Une.y - Un.y);
            e2 = k * ((Une.x - Un.x) + (Uc.y - Un.y));
            s0 = fC * (e0 + NU_C * e1); s1 = fC * (NU_C * e0 + e1); s2 = fC * hs * e2;
            fx += q * s0; fy += q * s2;
        }
        if (iok && j0) {    // T4: tri2(i,j-1), center = node b
            e0 = k * (Us.x - Uc.x);
            e1 = k * (Us.y - Usw.y);
            e2 = k * ((Us.x - Usw.x) + (Us.y - Uc.y));
            s0 = fC * (e0 + NU_C * e1); s1 = fC * (NU_C * e0 + e1); s2 = fC * hs * e2;
            fx -= q * s0; fy -= q * s2;
        }
        if (i0 && j0) {     // T5: tri2(i-1,j-1), center = node d
            e0 = k * (Uc.x - Un.x);
            e1 = k * (Uc.y - Uw.y);
            e2 = k * ((Uc.x - Uw.x) + (Uc.y - Un.y));
            s0 = fC * (e0 + NU_C * e1); s1 = fC * (NU_C * e0 + e1); s2 = fC * hs * e2;
            fx += q * (s0 + s2); fy += q * (s1 + s2);
        }
        if (i0 && jok) {    // T6: tri2(i-1,j), center = node c
            e0 = k * (Ue.x - Une.x);
            e1 = k * (Ue.y - Uc.y);
            e2 = k * ((Ue.x - Uc.x) + (Ue.y - Une.y));
            s0 = fC * (e0 + NU_C * e1); s1 = fC * (NU_C * e0 + e1); s2 = fC * hs * e2;
            fx -= q * s2; fy -= q * s1;
        }

        r2 = fx * fx + fy * fy;

        if (iok && jok) {
            const float2 Use = up[(size_t)ip * g + jp];
            const float2 Tc  = ut[(size_t)i  * g + j ];
            const float2 Te  = ut[(size_t)i  * g + jp];
            const float2 Ts  = ut[(size_t)ip * g + j ];
            const float2 Tse = ut[(size_t)ip * g + jp];
            const float dcx = Uc.x - Tc.x,   dcy = Uc.y - Tc.y;
            const float dex = Ue.x - Te.x,   dey = Ue.y - Te.y;
            const float dsx = Us.x - Ts.x,   dsy = Us.y - Ts.y;
            const float dqx = Use.x - Tse.x, dqy = Use.y - Tse.y;
            e0 = k * (dsx - dcx);
            e1 = k * (dey - dcy);
            e2 = k * ((dex - dcx) + (dsy - dcy));
            energy += area * fC * (e0 * e0 + 2.f * NU_C * e0 * e1 + e1 * e1 + hs * e2 * e2);
            e0 = k * (dqx - dex);
            e1 = k * (dqy - dsy);
            e2 = k * ((dqx - dsx) + (dqy - dey));
            energy += area * fC * (e0 * e0 + 2.f * NU_C * e0 * e1 + e1 * e1 + hs * e2 * e2);
        }
    }

    // block reduction (wave shuffle + LDS across 4 waves), ONE store/block
    for (int o = 32; o > 0; o >>= 1) {
        r2     += __shfl_down(r2, o, 64);
        energy += __shfl_down(energy, o, 64);
    }
    __shared__ float s_r[4], s_e[4];
    const int lane = threadIdx.x & 63;
    const int wv = threadIdx.x >> 6;
    if (lane == 0) { s_r[wv] = r2; s_e[wv] = energy; }
    __syncthreads();
    if (threadIdx.x == 0) {
        const int b = blockIdx.y * gridDim.x + blockIdx.x;
        partials[b] = make_float2(s_r[0] + s_r[1] + s_r[2] + s_r[3],
                                  s_e[0] + s_e[1] + s_e[2] + s_e[3]);
    }
}

__global__ __launch_bounds__(256)
void pino_reduce_kernel(const float2* __restrict__ partials,
                        float* __restrict__ out,
                        int nblocks, float inv_n2, float inv_ta) {
    float r = 0.f, e = 0.f;
    for (int b = threadIdx.x; b < nblocks; b += 256) {
        float2 p = partials[b];
        r += p.x;
        e += p.y;
    }
    for (int o = 32; o > 0; o >>= 1) {
        r += __shfl_down(r, o, 64);
        e += __shfl_down(e, o, 64);
    }
    __shared__ float sr[4], se[4];
    const int lane = threadIdx.x & 63;
    const int wv = threadIdx.x >> 6;
    if (lane == 0) { sr[wv] = r; se[wv] = e; }
    __syncthreads();
    if (threadIdx.x == 0) {
        out[0] = EQ_W * (sr[0] + sr[1] + sr[2] + sr[3]) * inv_n2 +
                 EN_W * (se[0] + se[1] + se[2] + se[3]) * inv_ta;
    }
}

extern "C" void kernel_launch(void* const* d_in, const int* in_sizes, int n_in,
                              void* d_out, int out_size, void* d_ws, size_t ws_size,
                              hipStream_t stream) {
    const float2* up = (const float2*)d_in[0];
    const float2* ut = (const float2*)d_in[1];
    const int N = in_sizes[0] / 2;           // nodes = g*g

    int g = 1;
    while (g * g < N) g++;                   // g = 1024

    const double h = 1.0 / (double)(g - 1);
    const float k = (float)((double)(g - 1));         // 1/h
    const float area = (float)(0.5 * h * h);          // per-triangle area
    const float q = (float)(0.5 * h);                 // area * k
    const double M = 2.0 * (double)(g - 1) * (double)(g - 1);
    const float inv_total_area = (float)(1.0 / (M * 0.5 * h * h));  // = 1.0
    const float inv_n2 = (float)(1.0 / (2.0 * (double)N));

    float2* partials = (float2*)d_ws;        // every slot overwritten -> no memset

    dim3 blk(256);
    dim3 grid((g + 63) / 64, (g + 3) / 4);
    const int nblocks = grid.x * grid.y;

    pino_stencil_kernel<<<grid, blk, 0, stream>>>(up, ut, partials, g, k, q, area);
    pino_reduce_kernel<<<1, blk, 0, stream>>>(partials, (float*)d_out,
                                              nblocks, inv_n2, inv_total_area);
}